// Round 5
// baseline (200.738 us; speedup 1.0000x reference)
//
#include <hip/hip_runtime.h>

namespace {
constexpr float SCALE = 0.17677669529663687f; // 32^-0.5

__device__ __forceinline__ void fma4(float4& acc, const float4& a,
                                     float bx, float by, float bz, float bw) {
  acc.x = fmaf(a.x, bx, acc.x);
  acc.y = fmaf(a.y, by, acc.y);
  acc.z = fmaf(a.z, bz, acc.z);
  acc.w = fmaf(a.w, bw, acc.w);
}
__device__ __forceinline__ float4 shflx(const float4& x, int m) {
  return make_float4(__shfl_xor(x.x, m, 64), __shfl_xor(x.y, m, 64),
                     __shfl_xor(x.z, m, 64), __shfl_xor(x.w, m, 64));
}
__device__ __forceinline__ float getc(const float4& a, int px) {
  return px == 0 ? a.x : px == 1 ? a.y : px == 2 ? a.z : a.w;
}

// Thread = (4-px group, head, 8-ch quarter). Wave = head; lane = cq*16+pxg.
// Per (ch,dy): 3 aligned float4 loads (L,C,R); dx-shifted tap vectors are
// register component selects. Block = 1 row x 4 heads; 1024 blocks.
__global__ __launch_bounds__(256, 4) void dilate_attn(
    const float* __restrict__ q, const float* __restrict__ k,
    const float* __restrict__ v, float* __restrict__ out) {
  __shared__ float4 smem[64 * 32];  // 64 px x 32 float4 chunks = 32 KB

  const int tid  = threadIdx.x;
  const int pxg  = tid & 15;         // pixel group (4 px each)
  const int cq   = (tid >> 4) & 3;   // channel quarter (8 ch)
  const int head = tid >> 6;         // wave = head

  // XCD swizzle: blk%8 -> XCD; each XCD owns 2 images, rows in order.
  const int blk  = blockIdx.x;
  const int xcd  = blk & 7;
  const int slot = blk >> 3;          // 0..127
  const int b    = xcd * 2 + (slot >> 6);
  const int h    = slot & 63;
  const int w0   = pxg << 2;

  // per-dy clamped row offsets + row masks (uniform per block)
  int rowi[3]; float my[3];
  #pragma unroll
  for (int dy = 0; dy < 3; ++dy) {
    const int ry = h + 2 * (dy - 1);
    const bool ok = (unsigned)ry < 64u;
    rowi[dy] = (ok ? ry : h) * 64;
    my[dy] = ok ? 1.0f : 0.0f;
  }
  // x columns (aligned) + per-pixel x masks
  const int   colL  = (pxg == 0)  ? w0 : w0 - 4;
  const int   colR  = (pxg == 15) ? w0 : w0 + 4;
  const float mxm01 = (pxg == 0)  ? 0.0f : 1.0f;  // dx=-2 invalid for px0,1
  const float mxp23 = (pxg == 15) ? 0.0f : 1.0f;  // dx=+2 invalid for px2,3

  const size_t cb = ((size_t)b * 128 + head * 32 + cq * 8) * 4096;
  const float* qb = q + cb + h * 64 + w0;
  const float* kb = k + cb;
  const float* vb = v + cb;

  // ---- Phase 1: partial logits over this thread's 8 channels ----
  float4 l[9];
  #pragma unroll
  for (int t = 0; t < 9; ++t) l[t] = make_float4(0.f, 0.f, 0.f, 0.f);

  #pragma unroll
  for (int c = 0; c < 8; ++c) {
    const float4 q4 = *(const float4*)(qb + c * 4096);
    const float* kc = kb + c * 4096;
    #pragma unroll
    for (int dy = 0; dy < 3; ++dy) {
      const float* kr = kc + rowi[dy];
      const float4 Lv = *(const float4*)(kr + colL);
      const float4 Cv = *(const float4*)(kr + w0);
      const float4 Rv = *(const float4*)(kr + colR);
      fma4(l[dy * 3 + 0], q4, Lv.z, Lv.w, Cv.x, Cv.y);   // dx=-2
      fma4(l[dy * 3 + 1], q4, Cv.x, Cv.y, Cv.z, Cv.w);   // dx= 0
      fma4(l[dy * 3 + 2], q4, Cv.z, Cv.w, Rv.x, Rv.y);   // dx=+2
    }
  }

  // combine the 4 channel-quarters (lanes cq*16+pxg, same wave)
  #pragma unroll
  for (int t = 0; t < 9; ++t) {
    float4 a = shflx(l[t], 16);
    l[t].x += a.x; l[t].y += a.y; l[t].z += a.z; l[t].w += a.w;
    a = shflx(l[t], 32);
    l[t].x += a.x; l[t].y += a.y; l[t].z += a.z; l[t].w += a.w;
  }

  // mask invalid taps to logit 0 (zero-padded keys stay in denominator)
  #pragma unroll
  for (int dy = 0; dy < 3; ++dy) {
    const float m0 = my[dy];
    l[dy*3+0].x *= m0 * mxm01; l[dy*3+0].y *= m0 * mxm01;
    l[dy*3+0].z *= m0;         l[dy*3+0].w *= m0;
    l[dy*3+1].x *= m0; l[dy*3+1].y *= m0; l[dy*3+1].z *= m0; l[dy*3+1].w *= m0;
    l[dy*3+2].x *= m0;         l[dy*3+2].y *= m0;
    l[dy*3+2].z *= m0 * mxp23; l[dy*3+2].w *= m0 * mxp23;
  }

  // ---- Phase 2: softmax over 9, per pixel component ----
  float4 mx = l[0];
  #pragma unroll
  for (int t = 1; t < 9; ++t) {
    mx.x = fmaxf(mx.x, l[t].x); mx.y = fmaxf(mx.y, l[t].y);
    mx.z = fmaxf(mx.z, l[t].z); mx.w = fmaxf(mx.w, l[t].w);
  }
  float4 s = make_float4(0.f, 0.f, 0.f, 0.f);
  #pragma unroll
  for (int t = 0; t < 9; ++t) {
    l[t].x = __expf((l[t].x - mx.x) * SCALE);
    l[t].y = __expf((l[t].y - mx.y) * SCALE);
    l[t].z = __expf((l[t].z - mx.z) * SCALE);
    l[t].w = __expf((l[t].w - mx.w) * SCALE);
    s.x += l[t].x; s.y += l[t].y; s.z += l[t].z; s.w += l[t].w;
  }
  const float4 r = make_float4(1.f / s.x, 1.f / s.y, 1.f / s.z, 1.f / s.w);
  #pragma unroll
  for (int t = 0; t < 9; ++t) {
    l[t].x *= r.x; l[t].y *= r.y; l[t].z *= r.z; l[t].w *= r.w;
  }
  // fold V-side zero-padding into the weights
  #pragma unroll
  for (int dy = 0; dy < 3; ++dy) {
    const float m0 = my[dy];
    l[dy*3+0].x *= m0 * mxm01; l[dy*3+0].y *= m0 * mxm01;
    l[dy*3+0].z *= m0;         l[dy*3+0].w *= m0;
    l[dy*3+1].x *= m0; l[dy*3+1].y *= m0; l[dy*3+1].z *= m0; l[dy*3+1].w *= m0;
    l[dy*3+2].x *= m0;         l[dy*3+2].y *= m0;
    l[dy*3+2].z *= m0 * mxp23; l[dy*3+2].w *= m0 * mxp23;
  }

  // ---- Phase 3: PV over 8 channels, in 2 pieces of 4 ch (VGPR control) ----
  #pragma unroll
  for (int pc = 0; pc < 2; ++pc) {
    float4 o[4];
    #pragma unroll
    for (int j = 0; j < 4; ++j) o[j] = make_float4(0.f, 0.f, 0.f, 0.f);
    #pragma unroll
    for (int j = 0; j < 4; ++j) {
      const float* vc = vb + (pc * 4 + j) * 4096;
      #pragma unroll
      for (int dy = 0; dy < 3; ++dy) {
        const float* vr = vc + rowi[dy];
        const float4 Lv = *(const float4*)(vr + colL);
        const float4 Cv = *(const float4*)(vr + w0);
        const float4 Rv = *(const float4*)(vr + colR);
        fma4(o[j], l[dy * 3 + 0], Lv.z, Lv.w, Cv.x, Cv.y);
        fma4(o[j], l[dy * 3 + 1], Cv.x, Cv.y, Cv.z, Cv.w);
        fma4(o[j], l[dy * 3 + 2], Cv.z, Cv.w, Rv.x, Rv.y);
      }
    }
    // register transpose (ch-major -> px-major) and LDS stage
    const int c4 = head * 8 + cq * 2 + pc;   // float4-chunk index 0..31
    #pragma unroll
    for (int px = 0; px < 4; ++px) {
      const int pg = w0 + px;
      smem[(pg << 5) | (c4 ^ (pg & 31))] =
          make_float4(getc(o[0], px), getc(o[1], px), getc(o[2], px), getc(o[3], px));
    }
  }

  __syncthreads();

  // ---- Coalesced store: one full row (32 KB contiguous) ----
  float4* outp = (float4*)(out + ((size_t)(b * 64 + h) * 64) * 128);
  #pragma unroll
  for (int it = 0; it < 8; ++it) {
    const int L = it * 256 + tid;
    const int px = L >> 5, c = L & 31;
    outp[L] = smem[(px << 5) | (c ^ (px & 31))];
  }
}
} // namespace

extern "C" void kernel_launch(void* const* d_in, const int* in_sizes, int n_in,
                              void* d_out, int out_size, void* d_ws, size_t ws_size,
                              hipStream_t stream) {
  const float* q = (const float*)d_in[0];
  const float* k = (const float*)d_in[1];
  const float* v = (const float*)d_in[2];
  float* o = (float*)d_out;
  dilate_attn<<<dim3(1024), dim3(256), 0, stream>>>(q, k, v, o);
}

// Round 6
// 144.112 us; speedup vs baseline: 1.3929x; 1.3929x over previous
//
#include <hip/hip_runtime.h>

namespace {
constexpr float SCALE = 0.17677669529663687f; // 32^-0.5
constexpr int CHP = 194; // padded LDS ch-plane stride (3*64 + 2): keeps b64 taps spread

// Block = (image b, head, row h). Stage k/v rows {h-2,h,h+2} x 32 ch into LDS
// once; serve the 9-tap reuse from LDS (b64 = 2 px via even dilation).
// Thread = (px-pair pp 0..31, 4-ch group cg 0..7); tid = cg | pp<<3 so the
// 8 cg-partials for a pixel sit in one wave (3-stage shfl_xor combine).
__global__ __launch_bounds__(256, 2) void dilate_attn(
    const float* __restrict__ q, const float* __restrict__ k,
    const float* __restrict__ v, float* __restrict__ out) {
  __shared__ float kbuf[32 * CHP];   // 24832 B
  __shared__ float vbuf[32 * CHP];   // 24832 B

  const int tid = threadIdx.x;
  const int cg  = tid & 7;    // 4-channel group
  const int pp  = tid >> 3;   // pixel pair (px0 = 2*pp)

  // XCD swizzle: blk&7 -> XCD; each XCD owns 8 (b,head) combos with rows in
  // order, so the 3x row-halo re-reads hit that XCD's L2.
  const int blk   = blockIdx.x;
  const int s     = blk >> 3;
  const int combo = ((blk & 7) << 3) | (s >> 6);  // 0..63
  const int h     = s & 63;
  const int b     = combo >> 2;
  const int head  = combo & 3;

  const size_t cb = ((size_t)b * 128 + head * 32) * 4096;
  const float* kp = k + cb;
  const float* vp = v + cb;

  // clamped rows + row masks (block-uniform)
  int rows[3]; float rowm[3];
  #pragma unroll
  for (int r = 0; r < 3; ++r) {
    const int ry = h + 2 * (r - 1);
    const bool ok = (unsigned)ry < 64u;
    rows[r] = (ok ? ry : h) * 64;
    rowm[r] = ok ? 1.0f : 0.0f;
  }

  // ---- q loads (independent of staging; overlap with it) ----
  const int px0 = pp << 1;
  float2 q2[4];
  #pragma unroll
  for (int ci = 0; ci < 4; ++ci)
    q2[ci] = *(const float2*)(q + cb + (cg * 4 + ci) * 4096 + h * 64 + px0);

  // ---- stage k,v: 32 ch x 3 rows x 64 px each (1536 float4 per tensor) ----
  #pragma unroll
  for (int t = 0; t < 6; ++t) {
    const int l4  = t * 256 + tid;      // f4 index 0..1535
    const int ch  = l4 / 48;            // 48 f4 per channel (3 rows x 16)
    const int rem = l4 - ch * 48;
    const int r   = rem >> 4;
    const int p4  = (rem & 15) << 2;
    const int go  = ch * 4096 + rows[r] + p4;
    const float4 k4 = *(const float4*)(kp + go);
    const float4 v4 = *(const float4*)(vp + go);
    const int wo = ch * CHP + r * 64 + p4;         // even -> 8B aligned
    ((float2*)(kbuf + wo))[0] = make_float2(k4.x, k4.y);
    ((float2*)(kbuf + wo))[1] = make_float2(k4.z, k4.w);
    ((float2*)(vbuf + wo))[0] = make_float2(v4.x, v4.y);
    ((float2*)(vbuf + wo))[1] = make_float2(v4.z, v4.w);
  }

  __syncthreads();

  // column taps (clamped, even -> 8B aligned) + x masks (same for both px)
  const int   txL = (pp == 0)  ? 0  : px0 - 2;
  const int   txC = px0;
  const int   txR = (pp == 31) ? 62 : px0 + 2;
  const float mL  = (pp == 0)  ? 0.0f : 1.0f;
  const float mR  = (pp == 31) ? 0.0f : 1.0f;

  // ---- Phase 1: partial logits over this thread's 4 channels ----
  float l0[9], l1[9];
  #pragma unroll
  for (int t = 0; t < 9; ++t) { l0[t] = 0.0f; l1[t] = 0.0f; }

  #pragma unroll
  for (int r = 0; r < 3; ++r) {
    #pragma unroll
    for (int ci = 0; ci < 4; ++ci) {
      const float* kc = kbuf + (cg * 4 + ci) * CHP + r * 64;
      const float2 kL = *(const float2*)(kc + txL);
      const float2 kC = *(const float2*)(kc + txC);
      const float2 kR = *(const float2*)(kc + txR);
      const float2 qq = q2[ci];
      l0[r*3+0] = fmaf(qq.x, kL.x, l0[r*3+0]);
      l1[r*3+0] = fmaf(qq.y, kL.y, l1[r*3+0]);
      l0[r*3+1] = fmaf(qq.x, kC.x, l0[r*3+1]);
      l1[r*3+1] = fmaf(qq.y, kC.y, l1[r*3+1]);
      l0[r*3+2] = fmaf(qq.x, kR.x, l0[r*3+2]);
      l1[r*3+2] = fmaf(qq.y, kR.y, l1[r*3+2]);
    }
  }

  // combine the 8 cg-partials (lane bits 0..2, same wave)
  #pragma unroll
  for (int m = 1; m <= 4; m <<= 1) {
    #pragma unroll
    for (int t = 0; t < 9; ++t) {
      l0[t] += __shfl_xor(l0[t], m, 64);
      l1[t] += __shfl_xor(l1[t], m, 64);
    }
  }

  // ---- Phase 2: mask + softmax over 9 (padded keys keep logit 0 in denom) ----
  float msk[9];
  #pragma unroll
  for (int r = 0; r < 3; ++r) {
    msk[r*3+0] = rowm[r] * mL;
    msk[r*3+1] = rowm[r];
    msk[r*3+2] = rowm[r] * mR;
  }
  float mx0 = -1e30f, mx1 = -1e30f;
  #pragma unroll
  for (int t = 0; t < 9; ++t) {
    l0[t] *= msk[t]; l1[t] *= msk[t];
    mx0 = fmaxf(mx0, l0[t]); mx1 = fmaxf(mx1, l1[t]);
  }
  float s0 = 0.0f, s1 = 0.0f;
  #pragma unroll
  for (int t = 0; t < 9; ++t) {
    l0[t] = __expf((l0[t] - mx0) * SCALE);
    l1[t] = __expf((l1[t] - mx1) * SCALE);
    s0 += l0[t]; s1 += l1[t];
  }
  const float r0 = 1.0f / s0, r1 = 1.0f / s1;
  #pragma unroll
  for (int t = 0; t < 9; ++t) {
    l0[t] *= r0 * msk[t];   // fold V zero-pad into weights
    l1[t] *= r1 * msk[t];
  }

  // ---- Phase 3: PV over this thread's 4 channels, from LDS ----
  float o0[4] = {0, 0, 0, 0}, o1[4] = {0, 0, 0, 0};
  #pragma unroll
  for (int r = 0; r < 3; ++r) {
    #pragma unroll
    for (int ci = 0; ci < 4; ++ci) {
      const float* vc = vbuf + (cg * 4 + ci) * CHP + r * 64;
      const float2 vL = *(const float2*)(vc + txL);
      const float2 vC = *(const float2*)(vc + txC);
      const float2 vR = *(const float2*)(vc + txR);
      o0[ci] = fmaf(l0[r*3+0], vL.x, o0[ci]);
      o0[ci] = fmaf(l0[r*3+1], vC.x, o0[ci]);
      o0[ci] = fmaf(l0[r*3+2], vR.x, o0[ci]);
      o1[ci] = fmaf(l1[r*3+0], vL.y, o1[ci]);
      o1[ci] = fmaf(l1[r*3+1], vC.y, o1[ci]);
      o1[ci] = fmaf(l1[r*3+2], vR.y, o1[ci]);
    }
  }

  // ---- Stores: per wave-instr, 8 px x 128B contiguous = full L2 lines ----
  float* ob = out + ((size_t)(b * 64 + h) * 64 + px0) * 128 + head * 32 + cg * 4;
  *(float4*)(ob)       = make_float4(o0[0], o0[1], o0[2], o0[3]);
  *(float4*)(ob + 128) = make_float4(o1[0], o1[1], o1[2], o1[3]);
}
} // namespace

extern "C" void kernel_launch(void* const* d_in, const int* in_sizes, int n_in,
                              void* d_out, int out_size, void* d_ws, size_t ws_size,
                              hipStream_t stream) {
  const float* q = (const float*)d_in[0];
  const float* k = (const float*)d_in[1];
  const float* v = (const float*)d_in[2];
  float* o = (float*)d_out;
  // 16 b x 4 heads x 64 rows = 4096 blocks
  dilate_attn<<<dim3(4096), dim3(256), 0, stream>>>(q, k, v, o);
}